// Round 1
// baseline (91.350 us; speedup 1.0000x reference)
//
#include <hip/hip_runtime.h>

// out[e] = dot(x[src[e]], x[dst[e]]), x: [N,128] f32, src/dst: [E] i32, out: [E] f32
// 32 lanes per edge: each lane loads one float4 of each operand row (32*16B = 512B = full row),
// 4 FMAs, then 5-step shfl_xor reduction within the 32-lane group. 2 edges per wave64.

__global__ __launch_bounds__(256) void edge_dot_kernel(
    const float* __restrict__ x,
    const int* __restrict__ src,
    const int* __restrict__ dst,
    float* __restrict__ out,
    int n_edges) {
    const int lane = threadIdx.x & 31;
    const int group = (blockIdx.x * blockDim.x + threadIdx.x) >> 5;
    const int n_groups = (gridDim.x * blockDim.x) >> 5;

    for (int e = group; e < n_edges; e += n_groups) {
        const int s = src[e];
        const int d = dst[e];
        const float4 a = reinterpret_cast<const float4*>(x + (size_t)s * 128)[lane];
        const float4 b = reinterpret_cast<const float4*>(x + (size_t)d * 128)[lane];
        float v = a.x * b.x + a.y * b.y + a.z * b.z + a.w * b.w;
        // reduce across the 32-lane group (xor offsets <= 16 stay within the group)
        #pragma unroll
        for (int off = 16; off; off >>= 1)
            v += __shfl_xor(v, off, 64);
        if (lane == 0) out[e] = v;
    }
}

extern "C" void kernel_launch(void* const* d_in, const int* in_sizes, int n_in,
                              void* d_out, int out_size, void* d_ws, size_t ws_size,
                              hipStream_t stream) {
    const float* x = (const float*)d_in[0];
    const int* src = (const int*)d_in[1];
    const int* dst = (const int*)d_in[2];
    float* out = (float*)d_out;
    const int n_edges = in_sizes[1];

    const int block = 256;
    const int edges_per_block = block / 32;  // 8
    int grid = (n_edges + edges_per_block - 1) / edges_per_block;
    if (grid > 2048) grid = 2048;  // grid-stride the rest
    edge_dot_kernel<<<grid, block, 0, stream>>>(x, src, dst, out, n_edges);
}

// Round 2
// 87.799 us; speedup vs baseline: 1.0404x; 1.0404x over previous
//
#include <hip/hip_runtime.h>

// out[e] = dot(x[src[e]], x[dst[e]]), x: [N,128] f32, src/dst: [E] i32, out: [E] f32
// 8 lanes per edge: each lane loads 4 float4 per operand row (8 lanes * 16B = 128B
// = one cache line per load group, 4 groups = full 512B row). 8 independent loads
// in flight per thread for MLP; 3-step shfl_xor reduce within the 8-lane group.
// 8 edges per wave64.

constexpr int LPE = 8;                 // lanes per edge
constexpr int V4 = 128 / 4 / LPE;      // float4 loads per row per lane = 4

__global__ __launch_bounds__(256) void edge_dot_kernel(
    const float* __restrict__ x,
    const int* __restrict__ src,
    const int* __restrict__ dst,
    float* __restrict__ out,
    int n_edges) {
    const int lane = threadIdx.x & (LPE - 1);
    const int group = (blockIdx.x * blockDim.x + threadIdx.x) / LPE;
    const int n_groups = (gridDim.x * blockDim.x) / LPE;

    for (int e = group; e < n_edges; e += n_groups) {
        const int s = src[e];
        const int d = dst[e];
        const float4* __restrict__ pa = reinterpret_cast<const float4*>(x + (size_t)s * 128);
        const float4* __restrict__ pb = reinterpret_cast<const float4*>(x + (size_t)d * 128);
        float4 a[V4], b[V4];
        #pragma unroll
        for (int k = 0; k < V4; ++k) a[k] = pa[lane + k * LPE];
        #pragma unroll
        for (int k = 0; k < V4; ++k) b[k] = pb[lane + k * LPE];
        float v = 0.f;
        #pragma unroll
        for (int k = 0; k < V4; ++k)
            v += a[k].x * b[k].x + a[k].y * b[k].y + a[k].z * b[k].z + a[k].w * b[k].w;
        // reduce across the 8-lane group (xor offsets < 8 stay within the group)
        #pragma unroll
        for (int off = LPE / 2; off; off >>= 1)
            v += __shfl_xor(v, off, 64);
        if (lane == 0) out[e] = v;
    }
}

extern "C" void kernel_launch(void* const* d_in, const int* in_sizes, int n_in,
                              void* d_out, int out_size, void* d_ws, size_t ws_size,
                              hipStream_t stream) {
    const float* x = (const float*)d_in[0];
    const int* src = (const int*)d_in[1];
    const int* dst = (const int*)d_in[2];
    float* out = (float*)d_out;
    const int n_edges = in_sizes[1];

    const int block = 256;
    int grid = 2048;  // grid-stride; ~9.5 edges per 8-lane group
    edge_dot_kernel<<<grid, block, 0, stream>>>(x, src, dst, out, n_edges);
}

// Round 3
// 57.800 us; speedup vs baseline: 1.5805x; 1.5190x over previous
//
#include <hip/hip_runtime.h>

// out[e] = dot(x[src[e]], x[dst[e]]), x: [N,128] f32 -> bf16-packed in ws, src/dst: [E] i32.
// Phase 1: cast x to bf16 (RNE) into d_ws (N*128*2 = 25.6 MB) — halves gather bytes
//          and the random-gather footprint (51.2 -> 25.6 MB, better L2 hit rate).
// Phase 2: 8 lanes/edge; each lane loads 2x16B (8 bf16 each) per operand row
//          (8 lanes * 16B = 128B = one cache line; row = 2 lines), unpack+FMA in fp32,
//          3-step shfl_xor reduce within the 8-lane group.

__device__ __forceinline__ unsigned short f2bf_rne(float f) {
    unsigned int b = __builtin_bit_cast(unsigned int, f);
    b += 0x7FFFu + ((b >> 16) & 1u);
    return (unsigned short)(b >> 16);
}

__global__ __launch_bounds__(256) void cast_bf16_kernel(
    const float* __restrict__ x, unsigned short* __restrict__ xb, int n_elems) {
    int i = (blockIdx.x * blockDim.x + threadIdx.x) * 8;
    if (i >= n_elems) return;
    const float4 a = reinterpret_cast<const float4*>(x + i)[0];
    const float4 b = reinterpret_cast<const float4*>(x + i)[1];
    ushort4 lo, hi;
    lo.x = f2bf_rne(a.x); lo.y = f2bf_rne(a.y); lo.z = f2bf_rne(a.z); lo.w = f2bf_rne(a.w);
    hi.x = f2bf_rne(b.x); hi.y = f2bf_rne(b.y); hi.z = f2bf_rne(b.z); hi.w = f2bf_rne(b.w);
    reinterpret_cast<ushort4*>(xb + i)[0] = lo;
    reinterpret_cast<ushort4*>(xb + i)[1] = hi;
}

// dot of 8 bf16 pairs packed as uint4 (2 bf16 per uint32)
__device__ __forceinline__ float dot8(uint4 a, uint4 b) {
    float acc = 0.f;
    const unsigned int* pa = &a.x;
    const unsigned int* pb = &b.x;
    #pragma unroll
    for (int i = 0; i < 4; ++i) {
        float alo = __builtin_bit_cast(float, pa[i] << 16);
        float ahi = __builtin_bit_cast(float, pa[i] & 0xFFFF0000u);
        float blo = __builtin_bit_cast(float, pb[i] << 16);
        float bhi = __builtin_bit_cast(float, pb[i] & 0xFFFF0000u);
        acc += alo * blo + ahi * bhi;
    }
    return acc;
}

constexpr int LPE = 8;  // lanes per edge

__global__ __launch_bounds__(256) void edge_dot_bf16_kernel(
    const unsigned short* __restrict__ xb,
    const int* __restrict__ src,
    const int* __restrict__ dst,
    float* __restrict__ out,
    int n_edges) {
    const int lane = threadIdx.x & (LPE - 1);
    const int group = (blockIdx.x * blockDim.x + threadIdx.x) / LPE;
    const int n_groups = (gridDim.x * blockDim.x) / LPE;

    for (int e = group; e < n_edges; e += n_groups) {
        const int s = src[e];
        const int d = dst[e];
        const uint4* __restrict__ pa = reinterpret_cast<const uint4*>(xb + (size_t)s * 128);
        const uint4* __restrict__ pb = reinterpret_cast<const uint4*>(xb + (size_t)d * 128);
        // row = 128 bf16 = 256B = 16 uint4; lane covers uint4 index lane and lane+8
        uint4 a0 = pa[lane], a1 = pa[lane + 8];
        uint4 b0 = pb[lane], b1 = pb[lane + 8];
        float v = dot8(a0, b0) + dot8(a1, b1);
        #pragma unroll
        for (int off = LPE / 2; off; off >>= 1)
            v += __shfl_xor(v, off, 64);
        if (lane == 0) out[e] = v;
    }
}

// fp32 fallback (used only if ws is too small for the bf16 table)
__global__ __launch_bounds__(256) void edge_dot_f32_kernel(
    const float* __restrict__ x,
    const int* __restrict__ src,
    const int* __restrict__ dst,
    float* __restrict__ out,
    int n_edges) {
    const int lane = threadIdx.x & (LPE - 1);
    const int group = (blockIdx.x * blockDim.x + threadIdx.x) / LPE;
    const int n_groups = (gridDim.x * blockDim.x) / LPE;

    for (int e = group; e < n_edges; e += n_groups) {
        const int s = src[e];
        const int d = dst[e];
        const float4* __restrict__ pa = reinterpret_cast<const float4*>(x + (size_t)s * 128);
        const float4* __restrict__ pb = reinterpret_cast<const float4*>(x + (size_t)d * 128);
        float v = 0.f;
        #pragma unroll
        for (int k = 0; k < 4; ++k) {
            float4 a = pa[lane + k * LPE];
            float4 b = pb[lane + k * LPE];
            v += a.x * b.x + a.y * b.y + a.z * b.z + a.w * b.w;
        }
        #pragma unroll
        for (int off = LPE / 2; off; off >>= 1)
            v += __shfl_xor(v, off, 64);
        if (lane == 0) out[e] = v;
    }
}

extern "C" void kernel_launch(void* const* d_in, const int* in_sizes, int n_in,
                              void* d_out, int out_size, void* d_ws, size_t ws_size,
                              hipStream_t stream) {
    const float* x = (const float*)d_in[0];
    const int* src = (const int*)d_in[1];
    const int* dst = (const int*)d_in[2];
    float* out = (float*)d_out;
    const int n_edges = in_sizes[1];
    const int n_elems = in_sizes[0];  // N * 128

    const size_t bf16_bytes = (size_t)n_elems * 2;
    if (ws_size >= bf16_bytes) {
        unsigned short* xb = (unsigned short*)d_ws;
        int cast_grid = (n_elems / 8 + 255) / 256;
        cast_bf16_kernel<<<cast_grid, 256, 0, stream>>>(x, xb, n_elems);
        edge_dot_bf16_kernel<<<2048, 256, 0, stream>>>(xb, src, dst, out, n_edges);
    } else {
        edge_dot_f32_kernel<<<2048, 256, 0, stream>>>(x, src, dst, out, n_edges);
    }
}

// Round 4
// 38.476 us; speedup vs baseline: 2.3742x; 1.5022x over previous
//
#include <hip/hip_runtime.h>

// out[e] = dot(x[src[e]], x[dst[e]]), x: [N,128] f32, src/dst: [E] i32, out: [E] f32.
// Phase 1: per-row int8 quantization into d_ws: q[n][k] = rint(x[n][k]/scale_n),
//          scale_n = rowmax/127. Row = 128 int8 = 128 B = ONE cache line.
//          Table: 12.8 MB (+400 KB scales) — much better L2 residency than bf16's 25.6 MB.
// Phase 2: 8 lanes/edge, each lane loads one uint4 (16 int8) per operand row,
//          4x v_dot4_i32_i8, 3-step shfl_xor reduce, rescale by scale_s*scale_d.

__device__ __forceinline__ int dot4i8(unsigned int a, unsigned int b, int acc) {
#if __has_builtin(__builtin_amdgcn_sdot4)
    return __builtin_amdgcn_sdot4((int)a, (int)b, acc, false);
#else
    #pragma unroll
    for (int i = 0; i < 4; ++i) {
        int av = (int)(a << (24 - 8 * i)) >> 24;
        int bv = (int)(b << (24 - 8 * i)) >> 24;
        acc += av * bv;
    }
    return acc;
#endif
}

// One 64-lane wave per row: lane i owns elements 2i, 2i+1.
__global__ __launch_bounds__(256) void quant_i8_kernel(
    const float* __restrict__ x,
    signed char* __restrict__ xq,
    float* __restrict__ scales,
    int n_rows) {
    const int lane = threadIdx.x & 63;
    const int wave = (blockIdx.x * blockDim.x + threadIdx.x) >> 6;
    const int n_waves = (gridDim.x * blockDim.x) >> 6;

    for (int r = wave; r < n_rows; r += n_waves) {
        const float2 v = reinterpret_cast<const float2*>(x + (size_t)r * 128)[lane];
        float m = fmaxf(fabsf(v.x), fabsf(v.y));
        #pragma unroll
        for (int off = 32; off; off >>= 1)
            m = fmaxf(m, __shfl_xor(m, off, 64));
        const float scale = m * (1.0f / 127.0f);
        const float inv = (m > 0.f) ? 127.0f / m : 0.f;
        int qa = (int)rintf(v.x * inv);
        int qb = (int)rintf(v.y * inv);
        qa = qa > 127 ? 127 : (qa < -127 ? -127 : qa);
        qb = qb > 127 ? 127 : (qb < -127 ? -127 : qb);
        unsigned short packed = (unsigned short)((qa & 0xFF) | ((qb & 0xFF) << 8));
        reinterpret_cast<unsigned short*>(xq + (size_t)r * 128)[lane] = packed;
        if (lane == 0) scales[r] = scale;
    }
}

constexpr int LPE = 8;  // lanes per edge

__global__ __launch_bounds__(256) void edge_dot_i8_kernel(
    const signed char* __restrict__ xq,
    const float* __restrict__ scales,
    const int* __restrict__ src,
    const int* __restrict__ dst,
    float* __restrict__ out,
    int n_edges) {
    const int lane = threadIdx.x & (LPE - 1);
    const int group = (blockIdx.x * blockDim.x + threadIdx.x) / LPE;
    const int n_groups = (gridDim.x * blockDim.x) / LPE;

    for (int e = group; e < n_edges; e += n_groups) {
        const int s = src[e];
        const int d = dst[e];
        const uint4 a = reinterpret_cast<const uint4*>(xq + (size_t)s * 128)[lane];
        const uint4 b = reinterpret_cast<const uint4*>(xq + (size_t)d * 128)[lane];
        int acc = 0;
        acc = dot4i8(a.x, b.x, acc);
        acc = dot4i8(a.y, b.y, acc);
        acc = dot4i8(a.z, b.z, acc);
        acc = dot4i8(a.w, b.w, acc);
        float v = (float)acc;
        #pragma unroll
        for (int off = LPE / 2; off; off >>= 1)
            v += __shfl_xor(v, off, 64);
        if (lane == 0) out[e] = v * scales[s] * scales[d];
    }
}

extern "C" void kernel_launch(void* const* d_in, const int* in_sizes, int n_in,
                              void* d_out, int out_size, void* d_ws, size_t ws_size,
                              hipStream_t stream) {
    const float* x = (const float*)d_in[0];
    const int* src = (const int*)d_in[1];
    const int* dst = (const int*)d_in[2];
    float* out = (float*)d_out;
    const int n_edges = in_sizes[1];
    const int n_elems = in_sizes[0];  // N * 128
    const int n_rows = n_elems / 128;

    signed char* xq = (signed char*)d_ws;                       // 12.8 MB
    float* scales = (float*)(xq + (size_t)n_elems);             // 400 KB

    quant_i8_kernel<<<2048, 256, 0, stream>>>(x, xq, scales, n_rows);
    edge_dot_i8_kernel<<<2048, 256, 0, stream>>>(xq, scales, src, dst, out, n_edges);
}